// Round 13
// baseline (33.385 us; speedup 1.0000x reference)
//
#include <hip/hip_runtime.h>

// LengthRegulator: out[b,c,t] = x[b,c,owner(b,t)]; owner is the unique token
// whose segment covers frame t (path = 0/1 disjoint segment mask tiling
// [0,T_OUT) -> bmm(x,path) == gather; exact). owner(b,t) monotone in t.
//
// Fused v6 = R12's banded TT=256 phase-1 + R2's good phase-2, no idx buffer:
//   grid (8, 32) = 256 blocks (1/CU) x 512 threads (8 waves).
//   Phase 1: anchor scans at t0 and t0+256 issued by tid<256 / tid>=256 in
//     parallel (one-hot columns -> exactly one hit each); band scan of
//     [o_lo,o_hi] (~33 rows avg) at 8 rows x 64 float4-cols per pass;
//     race-free conditional LDS store of owner per t.
//   Phase 2: lane's t-quad = 4*(tid&63) -> each wave-store is 1 KiB
//     contiguous; wave w writes channels c = w+8j (j=0..31); 4 gathers from
//     the L1/L2-resident 1 KiB x row per store. 256 KiB contiguous out per
//     block. No idx round-trip (-8 MiB reads), one dispatch (no drain).

#define LR_B 32
#define LR_C 256
#define LR_TIN 256
#define LR_TOUT 2048
#define TT 256

__global__ __launch_bounds__(512) void lr_fused6(const float* __restrict__ x,
                                                 const float* __restrict__ path,
                                                 float* __restrict__ out) {
    __shared__ int owner[TT];
    __shared__ int o_lo_s, o_hi_s;

    const int tid = threadIdx.x;
    const int t0 = blockIdx.x * TT;
    const int b  = blockIdx.y;
    const float* pb = path + (size_t)b * LR_TIN * LR_TOUT;

    // ---- phase 1a: anchor scans, both columns in parallel ----
    if (tid < LR_TIN) {
        if (pb[(size_t)tid * LR_TOUT + t0] != 0.0f) o_lo_s = tid;
    } else {
        const int r = tid - LR_TIN;
        if (t0 + TT < LR_TOUT) {
            if (pb[(size_t)r * LR_TOUT + t0 + TT] != 0.0f) o_hi_s = r;
        } else if (r == 0) {
            o_hi_s = LR_TIN - 1;
        }
    }
    __syncthreads();
    const int o_lo = o_lo_s;
    const int o_hi = o_hi_s;

    // ---- phase 1b: band scan, 8 rows x 64 float4-cols per pass ----
    const int col4 = tid & 63;           // float4 column within 256-t tile
    const int w = tid >> 6;              // wave 0..7
    for (int r = o_lo + w; r <= o_hi; r += 8) {
        const float4 v = *reinterpret_cast<const float4*>(
            pb + (size_t)r * LR_TOUT + t0 + 4 * col4);
        if (v.x != 0.0f) owner[4 * col4 + 0] = r;
        if (v.y != 0.0f) owner[4 * col4 + 1] = r;
        if (v.z != 0.0f) owner[4 * col4 + 2] = r;
        if (v.w != 0.0f) owner[4 * col4 + 3] = r;
    }
    __syncthreads();

    // ---- phase 2: expand all 256 channels, 1 KiB contiguous wave stores ----
    const int4 iv = *reinterpret_cast<const int4*>(&owner[4 * col4]);
    const float* xb = x + (size_t)b * LR_C * LR_TIN;
    float* ob = out + (size_t)b * LR_C * LR_TOUT + t0 + 4 * col4;
#pragma unroll 8
    for (int j = 0; j < LR_C / 8; ++j) {      // 32 iterations
        const int c = w + 8 * j;
        const float* xr = xb + (size_t)c * LR_TIN;
        float4 o;
        o.x = xr[iv.x];
        o.y = xr[iv.y];
        o.z = xr[iv.z];
        o.w = xr[iv.w];
        *reinterpret_cast<float4*>(ob + (size_t)c * LR_TOUT) = o;
    }
}

extern "C" void kernel_launch(void* const* d_in, const int* in_sizes, int n_in,
                              void* d_out, int out_size, void* d_ws, size_t ws_size,
                              hipStream_t stream) {
    const float* x    = (const float*)d_in[0];   // [B, C, T_IN] fp32
    const float* path = (const float*)d_in[1];   // [B, T_IN, T_OUT] fp32
    float* out = (float*)d_out;                  // [B, C, T_OUT] fp32
    lr_fused6<<<dim3(LR_TOUT / TT, LR_B), 512, 0, stream>>>(x, path, out);
}